// Round 11
// baseline (344.940 us; speedup 1.0000x reference)
//
#include <hip/hip_runtime.h>

typedef unsigned short u16;
typedef _Float16 f16x8 __attribute__((ext_vector_type(8)));
typedef float f32x4 __attribute__((ext_vector_type(4)));
typedef unsigned int u32x4 __attribute__((ext_vector_type(4)));

#define NB 8
#define NN 2048
#define ND 512
#define NHC 128
#define MTOT (NB*NN)      // 16384
#define CCH 768           // HC + HC + D

__device__ inline u16 f2h(float f) {
  _Float16 h = (_Float16)f;
  return __builtin_bit_cast(u16, h);
}
__device__ inline float h2f(u16 h) {
  return (float)__builtin_bit_cast(_Float16, h);
}

__device__ inline void gld_lds16(const void* g, void* l) {
  __builtin_amdgcn_global_load_lds(
      (__attribute__((address_space(1))) unsigned int*)(g),
      (__attribute__((address_space(3))) unsigned int*)(l), 16, 0, 0);
}

union U8 { u32x4 v; u16 h[8]; };

// ---------------- convert / assemble ----------------

__global__ void cvt_f32_f16(const float* __restrict__ in, u16* __restrict__ out, size_t n4) {
  size_t i = (size_t)blockIdx.x * 256 + threadIdx.x;
  if (i >= n4) return;
  float4 v = ((const float4*)in)[i];
  ushort4 o;
  o.x = f2h(v.x); o.y = f2h(v.y); o.z = f2h(v.z); o.w = f2h(v.w);
  ((ushort4*)out)[i] = o;
}

__global__ void assemble_w(const float* __restrict__ W1, const float* __restrict__ W2,
                           const float* __restrict__ W3, const float* __restrict__ b1,
                           const float* __restrict__ b2, const float* __restrict__ b3,
                           u16* __restrict__ Wcat, float* __restrict__ bcat) {
  int i = blockIdx.x * 256 + threadIdx.x;       // float4 groups: 768*512/4 = 98304
  if (i < 98304) {
    int e = i * 4;
    int rowc = e >> 9;
    int col  = e & 511;
    const float* src = rowc < 128 ? &W1[rowc * 512 + col]
                     : rowc < 256 ? &W2[(rowc - 128) * 512 + col]
                                  : &W3[(rowc - 256) * 512 + col];
    float4 v = *(const float4*)src;
    ushort4 o;
    o.x = f2h(v.x); o.y = f2h(v.y); o.z = f2h(v.z); o.w = f2h(v.w);
    *(ushort4*)&Wcat[e] = o;
  }
  if (i < 768) {
    bcat[i] = i < 128 ? b1[i] : i < 256 ? b2[i - 128] : b3[i - 256];
  }
}

// ---------------- proj GEMM (C[m,n] = sum_k A[m,k]*B[n,k]), m97 structure, fp16 ----------------

enum { EPI_NONE = 0, EPI_BIAS_LEAKY = 1 };

template <int EPI, int TM, int TN, bool OUT16>
__global__ __launch_bounds__(256)
void gemm_bt(const u16* __restrict__ A, const u16* __restrict__ B,
             void* __restrict__ Cv, int N, int K,
             size_t sA, size_t sB, size_t sC,
             const float* __restrict__ bias) {
  const int bz = blockIdx.z;
  A += (size_t)bz * sA;
  B += (size_t)bz * sB;
  const int row0 = blockIdx.x * TM, col0 = blockIdx.y * TN;
  __shared__ __attribute__((aligned(16))) u16 As[TM * 64];
  __shared__ __attribute__((aligned(16))) u16 Bs[TN * 64];
  const int tid  = threadIdx.x;
  const int lane = tid & 63;
  const int wave = tid >> 6;
  constexpr int MF = TM / 32, NF = TN / 32;
  const int wr = (wave >> 1) * (TM / 2), wc = (wave & 1) * (TN / 2);
  const int lr  = lane & 15;
  const int lk8 = (lane >> 4) * 8;
  f32x4 acc[MF][NF] = {};
  for (int kt = 0; kt < K; kt += 64) {
#pragma unroll
    for (int i = 0; i < TM / 32; ++i) {
      int e = i * 256 + tid;
      int r = e >> 3, kc = (e & 7) * 8;
      gld_lds16(A + (size_t)(row0 + r) * K + kt + kc, As + e * 8);
    }
#pragma unroll
    for (int i = 0; i < TN / 32; ++i) {
      int e = i * 256 + tid;
      int r = e >> 3, kc = (e & 7) * 8;
      gld_lds16(B + (size_t)(col0 + r) * K + kt + kc, Bs + e * 8);
    }
    __syncthreads();
#pragma unroll
    for (int kk = 0; kk < 2; ++kk) {
      f16x8 af[MF], bg[NF];
      const int ko = kk * 32 + lk8;
#pragma unroll
      for (int m = 0; m < MF; ++m)
        af[m] = __builtin_bit_cast(f16x8, *(const u32x4*)&As[(wr + m * 16 + lr) * 64 + ko]);
#pragma unroll
      for (int n = 0; n < NF; ++n)
        bg[n] = __builtin_bit_cast(f16x8, *(const u32x4*)&Bs[(wc + n * 16 + lr) * 64 + ko]);
#pragma unroll
      for (int m = 0; m < MF; ++m)
#pragma unroll
        for (int n = 0; n < NF; ++n)
          acc[m][n] = __builtin_amdgcn_mfma_f32_16x16x32_f16(af[m], bg[n], acc[m][n], 0, 0, 0);
    }
    __syncthreads();
  }
  const int lq4 = (lane >> 4) * 4;
#pragma unroll
  for (int m = 0; m < MF; ++m) {
#pragma unroll
    for (int n = 0; n < NF; ++n) {
      const int col = col0 + wc + n * 16 + lr;
#pragma unroll
      for (int r = 0; r < 4; ++r) {
        const int row = row0 + wr + m * 16 + lq4 + r;
        float v = acc[m][n][r];
        if (EPI == EPI_BIAS_LEAKY) { v += bias[col]; v = v >= 0.0f ? v : 0.01f * v; }
        if (OUT16) ((u16*)Cv)[(size_t)bz * sC + (size_t)row * N + col] = f2h(v);
        else       ((float*)Cv)[(size_t)bz * sC + (size_t)row * N + col] = v;
      }
    }
  }
}

// ---------------- one-shot S GEMM: ST[n][m] = X1[n].X2[m], K=128, 256x256 tile ----------------
// epilogue: fp16 store + per-(16-rowchunk) column max and column Z partials.

__global__ __launch_bounds__(512)
void gemm_s(const u16* __restrict__ X1, const u16* __restrict__ X2,
            u16* __restrict__ ST, float* __restrict__ Mpart, float* __restrict__ Zpart) {
  const int bz = blockIdx.z;
  X1 += (size_t)bz * NN * NHC;
  X2 += (size_t)bz * NN * NHC;
  u16* STb = ST + (size_t)bz * NN * NN;
  const int row0 = blockIdx.x * 256;   // n
  const int col0 = blockIdx.y * 256;   // m
  __shared__ __attribute__((aligned(16))) u16 As[256 * 128];
  __shared__ __attribute__((aligned(16))) u16 Bs[256 * 128];
  const int tid = threadIdx.x, lane = tid & 63, wave = tid >> 6;
  const int lr = lane & 15, lk8 = (lane >> 4) * 8;
  const int wr = (wave >> 2) * 128, wc = (wave & 3) * 64;
  // stage; source pre-swizzled so linear LDS + XOR read is bank-friendly (rule #21)
#pragma unroll
  for (int i = 0; i < 8; ++i) {
    int e = i * 512 + tid;
    int r = e >> 4;
    int kc = ((e & 15) ^ (r & 7)) * 8;
    gld_lds16(X1 + (size_t)(row0 + r) * NHC + kc, As + e * 8);
  }
#pragma unroll
  for (int i = 0; i < 8; ++i) {
    int e = i * 512 + tid;
    int r = e >> 4;
    int kc = ((e & 15) ^ (r & 7)) * 8;
    gld_lds16(X2 + (size_t)(col0 + r) * NHC + kc, Bs + e * 8);
  }
  __syncthreads();
  f32x4 acc[8][4] = {};
#pragma unroll
  for (int kk = 0; kk < 4; ++kk) {
    const int ko = kk * 32 + lk8;
    f16x8 af[8], bg[4];
#pragma unroll
    for (int m = 0; m < 8; ++m) {
      int rr = wr + m * 16 + lr;
      af[m] = __builtin_bit_cast(f16x8, *(const u32x4*)&As[rr * 128 + (ko ^ ((rr & 7) * 8))]);
    }
#pragma unroll
    for (int n = 0; n < 4; ++n) {
      int rr = wc + n * 16 + lr;
      bg[n] = __builtin_bit_cast(f16x8, *(const u32x4*)&Bs[rr * 128 + (ko ^ ((rr & 7) * 8))]);
    }
#pragma unroll
    for (int m = 0; m < 8; ++m)
#pragma unroll
      for (int n = 0; n < 4; ++n)
        acc[m][n] = __builtin_amdgcn_mfma_f32_16x16x32_f16(af[m], bg[n], acc[m][n], 0, 0, 0);
  }
  const int lq4 = (lane >> 4) * 4;
  const int chunk = blockIdx.x * 2 + (wave >> 2);   // 16 row-chunks of 128 per batch
  float mxl[4] = {-3.0e38f, -3.0e38f, -3.0e38f, -3.0e38f};
  // store pass: nf innermost so a lane's 4 stores per row are address-adjacent (L2 merge)
#pragma unroll
  for (int mf = 0; mf < 8; ++mf) {
#pragma unroll
    for (int r = 0; r < 4; ++r) {
      const int row = row0 + wr + mf * 16 + lq4 + r;
#pragma unroll
      for (int nf = 0; nf < 4; ++nf) {
        const int col = col0 + wc + nf * 16 + lr;
        u16 hq = f2h(acc[mf][nf][r]);
        STb[(size_t)row * NN + col] = hq;
        mxl[nf] = fmaxf(mxl[nf], h2f(hq));
      }
    }
  }
#pragma unroll
  for (int nf = 0; nf < 4; ++nf) {
    const int col = col0 + wc + nf * 16 + lr;
    float mx = mxl[nf];
    mx = fmaxf(mx, __shfl_xor(mx, 16));
    mx = fmaxf(mx, __shfl_xor(mx, 32));
    float s = 0.0f;
#pragma unroll
    for (int mf = 0; mf < 8; ++mf)
#pragma unroll
      for (int r = 0; r < 4; ++r)
        s += __expf(h2f(f2h(acc[mf][nf][r])) - mx);
    s += __shfl_xor(s, 16);
    s += __shfl_xor(s, 32);
    if (lane < 16) {
      size_t idx = (size_t)chunk * MTOT + (size_t)bz * NN + col;
      Mpart[idx] = mx;
      Zpart[idx] = s;
    }
  }
}

// combine 16 chunk partials: M = max, Z = sum exp(Mc-M)*Zc
__global__ void mzreduce(const float* __restrict__ Mpart, const float* __restrict__ Zpart,
                         float* __restrict__ Mrow, float* __restrict__ Zrow) {
  int i = blockIdx.x * 256 + threadIdx.x;   // 16384
  float M = Mpart[i];
#pragma unroll
  for (int c = 1; c < 16; ++c) M = fmaxf(M, Mpart[(size_t)c * MTOT + i]);
  float Z = 0.0f;
#pragma unroll
  for (int c = 0; c < 16; ++c)
    Z += __expf(Mpart[(size_t)c * MTOT + i] - M) * Zpart[(size_t)c * MTOT + i];
  Mrow[i] = M;
  Zrow[i] = Z;
}

// ---------------- fused PV GEMM: out[n][d] = sum_m exp(ST[n][m]-M[m]) * X3T'[d][m] + Xb[n][d]
// T3-minimum structure: prefetch(t+1) before compute(t), dbuf LDS, ONE barrier/K-step.
__global__ __launch_bounds__(256)
void gemm_pv(const u16* __restrict__ ST, const float* __restrict__ Mrow,
             const u16* __restrict__ X3T, const u16* __restrict__ Xb,
             float* __restrict__ out) {
  const int bz = blockIdx.z;
  const u16* Sb = ST + (size_t)bz * NN * NN;
  const u16* Bb = X3T + (size_t)bz * (size_t)ND * NN;
  const float* Mb = Mrow + bz * NN;
  const int row0 = blockIdx.x * 64;        // n tile
  const int col0 = blockIdx.y * 128;       // d tile
  __shared__ __attribute__((aligned(16))) u16 As[2][64 * 64];
  __shared__ __attribute__((aligned(16))) u16 Bs[2][128 * 64];
  const int tid = threadIdx.x, lane = tid & 63, wave = tid >> 6;
  const int wr = (wave >> 1) * 32, wc = (wave & 1) * 64;
  const int lr = lane & 15, lk8 = (lane >> 4) * 8;
  const int arow = tid >> 3;               // 0..31
  const int akc  = (tid & 7) * 8;          // 0..56
  f32x4 acc[2][4] = {};

  U8 cs0, cs1;
  float4 cM0, cM1;
  // prologue: stage tile 0
#pragma unroll
  for (int i = 0; i < 4; ++i) {
    int e = i * 256 + tid;
    int r = e >> 3, kc = (e & 7) * 8;
    gld_lds16(Bb + (size_t)(col0 + r) * NN + kc, &Bs[0][e * 8]);
  }
  cs0.v = *(const u32x4*)&Sb[(size_t)(row0 + arow) * NN + akc];
  cs1.v = *(const u32x4*)&Sb[(size_t)(row0 + arow + 32) * NN + akc];
  cM0 = *(const float4*)&Mb[akc];
  cM1 = *(const float4*)&Mb[akc + 4];
  {
    U8 p0, p1;
    p0.h[0] = f2h(__expf(h2f(cs0.h[0]) - cM0.x));
    p0.h[1] = f2h(__expf(h2f(cs0.h[1]) - cM0.y));
    p0.h[2] = f2h(__expf(h2f(cs0.h[2]) - cM0.z));
    p0.h[3] = f2h(__expf(h2f(cs0.h[3]) - cM0.w));
    p0.h[4] = f2h(__expf(h2f(cs0.h[4]) - cM1.x));
    p0.h[5] = f2h(__expf(h2f(cs0.h[5]) - cM1.y));
    p0.h[6] = f2h(__expf(h2f(cs0.h[6]) - cM1.z));
    p0.h[7] = f2h(__expf(h2f(cs0.h[7]) - cM1.w));
    p1.h[0] = f2h(__expf(h2f(cs1.h[0]) - cM0.x));
    p1.h[1] = f2h(__expf(h2f(cs1.h[1]) - cM0.y));
    p1.h[2] = f2h(__expf(h2f(cs1.h[2]) - cM0.z));
    p1.h[3] = f2h(__expf(h2f(cs1.h[3]) - cM0.w));
    p1.h[4] = f2h(__expf(h2f(cs1.h[4]) - cM1.x));
    p1.h[5] = f2h(__expf(h2f(cs1.h[5]) - cM1.y));
    p1.h[6] = f2h(__expf(h2f(cs1.h[6]) - cM1.z));
    p1.h[7] = f2h(__expf(h2f(cs1.h[7]) - cM1.w));
    *(u32x4*)&As[0][arow * 64 + akc] = p0.v;
    *(u32x4*)&As[0][(arow + 32) * 64 + akc] = p1.v;
  }
  __syncthreads();

  int buf = 0;
  for (int t = 0; t < NN / 64; ++t) {
    const int ktn = (t + 1) * 64;
    U8 ns0, ns1;
    float4 nM0, nM1;
    if (t < NN / 64 - 1) {
      // issue next-tile loads BEFORE compute (latency hides under MFMA)
#pragma unroll
      for (int i = 0; i < 4; ++i) {
        int e = i * 256 + tid;
        int r = e >> 3, kc = (e & 7) * 8;
        gld_lds16(Bb + (size_t)(col0 + r) * NN + ktn + kc, &Bs[buf ^ 1][e * 8]);
      }
      ns0.v = *(const u32x4*)&Sb[(size_t)(row0 + arow) * NN + ktn + akc];
      ns1.v = *(const u32x4*)&Sb[(size_t)(row0 + arow + 32) * NN + ktn + akc];
      nM0 = *(const float4*)&Mb[ktn + akc];
      nM1 = *(const float4*)&Mb[ktn + akc + 4];
    }
    // compute on current buffers
    const u16* Ab = &As[buf][0];
    const u16* Bbs = &Bs[buf][0];
#pragma unroll
    for (int kk = 0; kk < 2; ++kk) {
      f16x8 af[2], bg[4];
      const int ko = kk * 32 + lk8;
#pragma unroll
      for (int m = 0; m < 2; ++m)
        af[m] = __builtin_bit_cast(f16x8, *(const u32x4*)&Ab[(wr + m * 16 + lr) * 64 + ko]);
#pragma unroll
      for (int n = 0; n < 4; ++n)
        bg[n] = __builtin_bit_cast(f16x8, *(const u32x4*)&Bbs[(wc + n * 16 + lr) * 64 + ko]);
#pragma unroll
      for (int m = 0; m < 2; ++m)
#pragma unroll
        for (int n = 0; n < 4; ++n)
          acc[m][n] = __builtin_amdgcn_mfma_f32_16x16x32_f16(af[m], bg[n], acc[m][n], 0, 0, 0);
    }
    if (t < NN / 64 - 1) {
      // exp + write next A tile into the other buffer
      U8 p0, p1;
      p0.h[0] = f2h(__expf(h2f(ns0.h[0]) - nM0.x));
      p0.h[1] = f2h(__expf(h2f(ns0.h[1]) - nM0.y));
      p0.h[2] = f2h(__expf(h2f(ns0.h[2]) - nM0.z));
      p0.h[3] = f2h(__expf(h2f(ns0.h[3]) - nM0.w));
      p0.h[4] = f2h(__expf(h2f(ns0.h[4]) - nM1.x));
      p0.h[5] = f2h(__expf(h2f(ns0.h[5]) - nM1.y));
      p0.h[6] = f2h(__expf(h2f(ns0.h[6]) - nM1.z));
      p0.h[7] = f2h(__expf(h2f(ns0.h[7]) - nM1.w));
      p1.h[0] = f2h(__expf(h2f(ns1.h[0]) - nM0.x));
      p1.h[1] = f2h(__expf(h2f(ns1.h[1]) - nM0.y));
      p1.h[2] = f2h(__expf(h2f(ns1.h[2]) - nM0.z));
      p1.h[3] = f2h(__expf(h2f(ns1.h[3]) - nM0.w));
      p1.h[4] = f2h(__expf(h2f(ns1.h[4]) - nM1.x));
      p1.h[5] = f2h(__expf(h2f(ns1.h[5]) - nM1.y));
      p1.h[6] = f2h(__expf(h2f(ns1.h[6]) - nM1.z));
      p1.h[7] = f2h(__expf(h2f(ns1.h[7]) - nM1.w));
      *(u32x4*)&As[buf ^ 1][arow * 64 + akc] = p0.v;
      *(u32x4*)&As[buf ^ 1][(arow + 32) * 64 + akc] = p1.v;
    }
    __syncthreads();   // single barrier per K-step (drains vmcnt for B, lgkm for A)
    buf ^= 1;
  }
  const int lq4 = (lane >> 4) * 4;
#pragma unroll
  for (int m = 0; m < 2; ++m) {
#pragma unroll
    for (int n = 0; n < 4; ++n) {
      const int col = col0 + wc + n * 16 + lr;
#pragma unroll
      for (int r = 0; r < 4; ++r) {
        const int row = row0 + wr + m * 16 + lq4 + r;
        float v = acc[m][n][r] + h2f(Xb[((size_t)bz * NN + row) * ND + col]);
        out[((size_t)bz * NN + row) * (size_t)ND + col] = v;
      }
    }
  }
}

// ---------------- BatchNorm stats / apply (Y in fp16) ----------------

__global__ void bn_stats(const u16* __restrict__ Yh, float* __restrict__ sums) {
  // 512 blocks x 192 threads; thread owns channel quad t; block owns 32 rows
  int t = threadIdx.x;                       // 0..191
  const ushort4* p = (const ushort4*)Yh + (size_t)blockIdx.x * 32 * 192 + t;
  float s0 = 0, s1 = 0, s2 = 0, s3 = 0, q0 = 0, q1 = 0, q2 = 0, q3 = 0;
  for (int r = 0; r < 32; ++r) {
    ushort4 v = p[(size_t)r * 192];
    float a = h2f(v.x), b = h2f(v.y), c = h2f(v.z), d = h2f(v.w);
    s0 += a; s1 += b; s2 += c; s3 += d;
    q0 += a * a; q1 += b * b; q2 += c * c; q3 += d * d;
  }
  int c = t * 4;
  atomicAdd(&sums[c + 0], s0); atomicAdd(&sums[c + 1], s1);
  atomicAdd(&sums[c + 2], s2); atomicAdd(&sums[c + 3], s3);
  atomicAdd(&sums[CCH + c + 0], q0); atomicAdd(&sums[CCH + c + 1], q1);
  atomicAdd(&sums[CCH + c + 2], q2); atomicAdd(&sums[CCH + c + 3], q3);
}

__global__ void bn_finalize(const float* __restrict__ sums,
                            const float* __restrict__ g1, const float* __restrict__ be1,
                            const float* __restrict__ g2, const float* __restrict__ be2,
                            const float* __restrict__ g3, const float* __restrict__ be3,
                            float* __restrict__ scale, float* __restrict__ shift) {
  int c = blockIdx.x * 256 + threadIdx.x;
  if (c >= CCH) return;
  const float inv = 1.0f / (float)MTOT;
  float mu  = sums[c] * inv;
  float var = sums[CCH + c] * inv - mu * mu;
  float g, be;
  if (c < 128)      { g = g1[c];       be = be1[c]; }
  else if (c < 256) { g = g2[c - 128]; be = be2[c - 128]; }
  else              { g = g3[c - 256]; be = be3[c - 256]; }
  float sc = rsqrtf(var + 1e-5f) * g;
  scale[c] = sc;
  shift[c] = be - mu * sc;
}

__global__ void bn_apply_route(const u16* __restrict__ Yh, const float* __restrict__ scale,
                               const float* __restrict__ shift, u16* __restrict__ X1b,
                               u16* __restrict__ X2b, u16* __restrict__ X3b) {
  size_t idx4 = (size_t)blockIdx.x * 256 + threadIdx.x;   // 16384*192 total
  int row = (int)(idx4 / 192);
  int c4  = (int)(idx4 % 192);
  int c   = c4 * 4;
  ushort4 y = ((const ushort4*)Yh)[idx4];
  float4 sc = ((const float4*)scale)[c4];
  float4 sh = ((const float4*)shift)[c4];
  ushort4 o;
  o.x = f2h(h2f(y.x) * sc.x + sh.x);
  o.y = f2h(h2f(y.y) * sc.y + sh.y);
  o.z = f2h(h2f(y.z) * sc.z + sh.z);
  o.w = f2h(h2f(y.w) * sc.w + sh.w);
  if (c < 128)      *(ushort4*)&X1b[(size_t)row * 128 + c] = o;
  else if (c < 256) *(ushort4*)&X2b[(size_t)row * 128 + (c - 128)] = o;
  else              *(ushort4*)&X3b[(size_t)row * 512 + (c - 256)] = o;
}

// ---------------- X3 transpose with 1/Z fold ----------------

__global__ void transpose_scale(const u16* __restrict__ in, const float* __restrict__ Zrow,
                                u16* __restrict__ out, int R, int C) {
  // per-batch [R][C] -> [C][R], scaling row m by 1/Zrow[bz*R+m]
  __shared__ u16 tile[64][66];
  int bz = blockIdx.z;
  const u16* ib = in + (size_t)bz * R * C;
  u16* ob = out + (size_t)bz * R * C;
  int r0 = blockIdx.x * 64, c0 = blockIdx.y * 64;
  int t = threadIdx.x, tr = t >> 4, tc4 = (t & 15) * 4;
#pragma unroll
  for (int i = 0; i < 4; ++i) {
    int rl = i * 16 + tr;
    float iz = 1.0f / Zrow[(size_t)bz * R + r0 + rl];
    ushort4 v = *(const ushort4*)&ib[(size_t)(r0 + rl) * C + c0 + tc4];
    tile[tc4 + 0][rl] = f2h(h2f(v.x) * iz);
    tile[tc4 + 1][rl] = f2h(h2f(v.y) * iz);
    tile[tc4 + 2][rl] = f2h(h2f(v.z) * iz);
    tile[tc4 + 3][rl] = f2h(h2f(v.w) * iz);
  }
  __syncthreads();
#pragma unroll
  for (int i = 0; i < 4; ++i) {
    int cl = i * 16 + tr;
    ushort4 o;
    o.x = tile[cl][tc4 + 0]; o.y = tile[cl][tc4 + 1];
    o.z = tile[cl][tc4 + 2]; o.w = tile[cl][tc4 + 3];
    *(ushort4*)&ob[(size_t)(c0 + cl) * R + r0 + tc4] = o;
  }
}

// ---------------- launch ----------------

extern "C" void kernel_launch(void* const* d_in, const int* in_sizes, int n_in,
                              void* d_out, int out_size, void* d_ws, size_t ws_size,
                              hipStream_t stream) {
  const float* X   = (const float*)d_in[0];
  const float* W1  = (const float*)d_in[1];
  const float* b1  = (const float*)d_in[2];
  const float* g1  = (const float*)d_in[3];
  const float* be1 = (const float*)d_in[4];
  const float* W2  = (const float*)d_in[5];
  const float* b2  = (const float*)d_in[6];
  const float* g2  = (const float*)d_in[7];
  const float* be2 = (const float*)d_in[8];
  const float* W3  = (const float*)d_in[9];
  const float* b3  = (const float*)d_in[10];
  const float* g3  = (const float*)d_in[11];
  const float* be3 = (const float*)d_in[12];
  float* out = (float*)d_out;

  char* ws = (char*)d_ws;
  // small region
  float* sums  = (float*)ws;                 // 1536
  float* scale = sums + 1536;                // 768
  float* shift = scale + 768;                // 768
  float* bcat  = shift + 768;                // 768
  float* Mrow  = bcat + 768;                 // 16384
  float* Zrow  = Mrow + 16384;               // 16384
  float* Mpart = Zrow + 16384;               // 16*16384
  float* Zpart = Mpart + 16 * 16384;         // 16*16384
  size_t off = (size_t)(1536 + 768 + 768 + 768 + 16384 + 16384 + 32 * 16384) * 4;
  // persistent fp16 region
  u16* X1b = (u16*)(ws + off); off += (size_t)MTOT * 128 * 2;
  u16* X2b = (u16*)(ws + off); off += (size_t)MTOT * 128 * 2;
  u16* X3b = (u16*)(ws + off); off += (size_t)MTOT * 512 * 2;
  u16* X3T = (u16*)(ws + off); off += (size_t)MTOT * 512 * 2;
  u16* Xb  = (u16*)(ws + off); off += (size_t)MTOT * 512 * 2;
  // union region: {Wcat, Yh} (dead before ST is written) overlaid with fp16 ST
  char* uni = ws + off;
  u16* Wcat = (u16*)uni;                               // 768 KB
  u16* Yh   = (u16*)(uni + 768 * 512 * 2);             // 24 MB fp16
  u16* ST   = (u16*)uni;                               // 64 MB fp16
  size_t total = off + (size_t)NB * NN * NN * 2;
  if (ws_size < total) return;  // workspace too small: fail visibly

  hipMemsetAsync(sums, 0, 1536 * sizeof(float), stream);

  cvt_f32_f16<<<8192, 256, 0, stream>>>(X, Xb, (size_t)MTOT * 512 / 4);
  assemble_w<<<384, 256, 0, stream>>>(W1, W2, W3, b1, b2, b3, Wcat, bcat);

  // proj GEMM: Yh[16384][768] = fp16(leaky(Xb @ Wcat^T + bcat))
  gemm_bt<EPI_BIAS_LEAKY, 128, 128, true><<<dim3(128, 6, 1), 256, 0, stream>>>(
      Xb, Wcat, Yh, CCH, 512, 0, 0, 0, bcat);

  bn_stats<<<512, 192, 0, stream>>>(Yh, sums);
  bn_finalize<<<3, 256, 0, stream>>>(sums, g1, be1, g2, be2, g3, be3, scale, shift);
  bn_apply_route<<<12288, 256, 0, stream>>>(Yh, scale, shift, X1b, X2b, X3b);

  // ST[b][n][m] = fp16(X1[b,n] . X2[b,m]) one-shot + col-max/Z partials
  gemm_s<<<dim3(8, 8, 8), 512, 0, stream>>>(X1b, X2b, ST, Mpart, Zpart);
  mzreduce<<<64, 256, 0, stream>>>(Mpart, Zpart, Mrow, Zrow);

  // X3T[d][m] = fp16(X3[m][d] / Z[m])
  transpose_scale<<<dim3(32, 8, 8), 256, 0, stream>>>(X3b, Zrow, X3T, 2048, 512);

  // out[b][n][d] = sum_m exp(ST[n][m]-M[m]) * X3T[d][m] + Xb[n][d]
  gemm_pv<<<dim3(32, 4, 8), 256, 0, stream>>>(ST, Mrow, X3T, Xb, out);
}

// Round 13
// 288.000 us; speedup vs baseline: 1.1977x; 1.1977x over previous
//
#include <hip/hip_runtime.h>

typedef unsigned short u16;
typedef _Float16 f16x8 __attribute__((ext_vector_type(8)));
typedef float f32x4 __attribute__((ext_vector_type(4)));
typedef unsigned int u32x4 __attribute__((ext_vector_type(4)));

#define NB 8
#define NN 2048
#define ND 512
#define NHC 128
#define MTOT (NB*NN)      // 16384
#define CCH 768           // HC + HC + D

__device__ inline u16 f2h(float f) {
  _Float16 h = (_Float16)f;
  return __builtin_bit_cast(u16, h);
}
__device__ inline float h2f(u16 h) {
  return (float)__builtin_bit_cast(_Float16, h);
}

__device__ inline void gld_lds16(const void* g, void* l) {
  __builtin_amdgcn_global_load_lds(
      (__attribute__((address_space(1))) unsigned int*)(g),
      (__attribute__((address_space(3))) unsigned int*)(l), 16, 0, 0);
}

union U8 { u32x4 v; u16 h[8]; };

// ---------------- convert / assemble ----------------

__global__ void cvt_f32_f16(const float* __restrict__ in, u16* __restrict__ out, size_t n4) {
  size_t i = (size_t)blockIdx.x * 256 + threadIdx.x;
  if (i >= n4) return;
  float4 v = ((const float4*)in)[i];
  ushort4 o;
  o.x = f2h(v.x); o.y = f2h(v.y); o.z = f2h(v.z); o.w = f2h(v.w);
  ((ushort4*)out)[i] = o;
}

__global__ void assemble_w(const float* __restrict__ W1, const float* __restrict__ W2,
                           const float* __restrict__ W3, const float* __restrict__ b1,
                           const float* __restrict__ b2, const float* __restrict__ b3,
                           u16* __restrict__ Wcat, float* __restrict__ bcat) {
  int i = blockIdx.x * 256 + threadIdx.x;       // float4 groups: 768*512/4 = 98304
  if (i < 98304) {
    int e = i * 4;
    int rowc = e >> 9;
    int col  = e & 511;
    const float* src = rowc < 128 ? &W1[rowc * 512 + col]
                     : rowc < 256 ? &W2[(rowc - 128) * 512 + col]
                                  : &W3[(rowc - 256) * 512 + col];
    float4 v = *(const float4*)src;
    ushort4 o;
    o.x = f2h(v.x); o.y = f2h(v.y); o.z = f2h(v.z); o.w = f2h(v.w);
    *(ushort4*)&Wcat[e] = o;
  }
  if (i < 768) {
    bcat[i] = i < 128 ? b1[i] : i < 256 ? b2[i - 128] : b3[i - 256];
  }
}

// ---------------- proj GEMM (C[m,n] = sum_k A[m,k]*B[n,k]), m97 structure, fp16 ----------------

enum { EPI_NONE = 0, EPI_BIAS_LEAKY = 1 };

template <int EPI, int TM, int TN, bool OUT16>
__global__ __launch_bounds__(256)
void gemm_bt(const u16* __restrict__ A, const u16* __restrict__ B,
             void* __restrict__ Cv, int N, int K,
             size_t sA, size_t sB, size_t sC,
             const float* __restrict__ bias) {
  const int bz = blockIdx.z;
  A += (size_t)bz * sA;
  B += (size_t)bz * sB;
  const int row0 = blockIdx.x * TM, col0 = blockIdx.y * TN;
  __shared__ __attribute__((aligned(16))) u16 As[TM * 64];
  __shared__ __attribute__((aligned(16))) u16 Bs[TN * 64];
  const int tid  = threadIdx.x;
  const int lane = tid & 63;
  const int wave = tid >> 6;
  constexpr int MF = TM / 32, NF = TN / 32;
  const int wr = (wave >> 1) * (TM / 2), wc = (wave & 1) * (TN / 2);
  const int lr  = lane & 15;
  const int lk8 = (lane >> 4) * 8;
  f32x4 acc[MF][NF] = {};
  for (int kt = 0; kt < K; kt += 64) {
#pragma unroll
    for (int i = 0; i < TM / 32; ++i) {
      int e = i * 256 + tid;
      int r = e >> 3, kc = (e & 7) * 8;
      gld_lds16(A + (size_t)(row0 + r) * K + kt + kc, As + e * 8);
    }
#pragma unroll
    for (int i = 0; i < TN / 32; ++i) {
      int e = i * 256 + tid;
      int r = e >> 3, kc = (e & 7) * 8;
      gld_lds16(B + (size_t)(col0 + r) * K + kt + kc, Bs + e * 8);
    }
    __syncthreads();
#pragma unroll
    for (int kk = 0; kk < 2; ++kk) {
      f16x8 af[MF], bg[NF];
      const int ko = kk * 32 + lk8;
#pragma unroll
      for (int m = 0; m < MF; ++m)
        af[m] = __builtin_bit_cast(f16x8, *(const u32x4*)&As[(wr + m * 16 + lr) * 64 + ko]);
#pragma unroll
      for (int n = 0; n < NF; ++n)
        bg[n] = __builtin_bit_cast(f16x8, *(const u32x4*)&Bs[(wc + n * 16 + lr) * 64 + ko]);
#pragma unroll
      for (int m = 0; m < MF; ++m)
#pragma unroll
        for (int n = 0; n < NF; ++n)
          acc[m][n] = __builtin_amdgcn_mfma_f32_16x16x32_f16(af[m], bg[n], acc[m][n], 0, 0, 0);
    }
    __syncthreads();
  }
  const int lq4 = (lane >> 4) * 4;
#pragma unroll
  for (int m = 0; m < MF; ++m) {
#pragma unroll
    for (int n = 0; n < NF; ++n) {
      const int col = col0 + wc + n * 16 + lr;
#pragma unroll
      for (int r = 0; r < 4; ++r) {
        const int row = row0 + wr + m * 16 + lq4 + r;
        float v = acc[m][n][r];
        if (EPI == EPI_BIAS_LEAKY) { v += bias[col]; v = v >= 0.0f ? v : 0.01f * v; }
        if (OUT16) ((u16*)Cv)[(size_t)bz * sC + (size_t)row * N + col] = f2h(v);
        else       ((float*)Cv)[(size_t)bz * sC + (size_t)row * N + col] = v;
      }
    }
  }
}

// ---------------- one-shot S GEMM, K=128, 256x256 tile ----------------
// Stores E'[n][m] = fp16(exp(acc - M_chunk[m])) (chunk = 128 n-rows);
// emits per-chunk column max (Mpart) and column Z partials (Zpart, from quantized E').

__global__ __launch_bounds__(512)
void gemm_s(const u16* __restrict__ X1, const u16* __restrict__ X2,
            u16* __restrict__ ST, float* __restrict__ Mpart, float* __restrict__ Zpart) {
  const int bz = blockIdx.z;
  X1 += (size_t)bz * NN * NHC;
  X2 += (size_t)bz * NN * NHC;
  u16* STb = ST + (size_t)bz * NN * NN;
  const int row0 = blockIdx.x * 256;   // n
  const int col0 = blockIdx.y * 256;   // m
  __shared__ __attribute__((aligned(16))) u16 As[256 * 128];
  __shared__ __attribute__((aligned(16))) u16 Bs[256 * 128];
  const int tid = threadIdx.x, lane = tid & 63, wave = tid >> 6;
  const int lr = lane & 15, lk8 = (lane >> 4) * 8;
  const int wr = (wave >> 2) * 128, wc = (wave & 3) * 64;
  // stage; source pre-swizzled so linear LDS + XOR read is bank-friendly (rule #21)
#pragma unroll
  for (int i = 0; i < 8; ++i) {
    int e = i * 512 + tid;
    int r = e >> 4;
    int kc = ((e & 15) ^ (r & 7)) * 8;
    gld_lds16(X1 + (size_t)(row0 + r) * NHC + kc, As + e * 8);
  }
#pragma unroll
  for (int i = 0; i < 8; ++i) {
    int e = i * 512 + tid;
    int r = e >> 4;
    int kc = ((e & 15) ^ (r & 7)) * 8;
    gld_lds16(X2 + (size_t)(col0 + r) * NHC + kc, Bs + e * 8);
  }
  __syncthreads();
  f32x4 acc[8][4] = {};
#pragma unroll
  for (int kk = 0; kk < 4; ++kk) {
    const int ko = kk * 32 + lk8;
    f16x8 af[8], bg[4];
#pragma unroll
    for (int m = 0; m < 8; ++m) {
      int rr = wr + m * 16 + lr;
      af[m] = __builtin_bit_cast(f16x8, *(const u32x4*)&As[rr * 128 + (ko ^ ((rr & 7) * 8))]);
    }
#pragma unroll
    for (int n = 0; n < 4; ++n) {
      int rr = wc + n * 16 + lr;
      bg[n] = __builtin_bit_cast(f16x8, *(const u32x4*)&Bs[rr * 128 + (ko ^ ((rr & 7) * 8))]);
    }
#pragma unroll
    for (int m = 0; m < 8; ++m)
#pragma unroll
      for (int n = 0; n < 4; ++n)
        acc[m][n] = __builtin_amdgcn_mfma_f32_16x16x32_f16(af[m], bg[n], acc[m][n], 0, 0, 0);
  }
  const int lq4 = (lane >> 4) * 4;
  const int chunk = blockIdx.x * 2 + (wave >> 2);   // 16 row-chunks of 128 per batch
#pragma unroll
  for (int nf = 0; nf < 4; ++nf) {
    const int col = col0 + wc + nf * 16 + lr;
    float mx = -3.0e38f;
#pragma unroll
    for (int mf = 0; mf < 8; ++mf)
#pragma unroll
      for (int r = 0; r < 4; ++r) mx = fmaxf(mx, acc[mf][nf][r]);
    mx = fmaxf(mx, __shfl_xor(mx, 16));
    mx = fmaxf(mx, __shfl_xor(mx, 32));   // max over the chunk's 128 rows
    float s = 0.0f;
#pragma unroll
    for (int mf = 0; mf < 8; ++mf) {
#pragma unroll
      for (int r = 0; r < 4; ++r) {
        const int row = row0 + wr + mf * 16 + lq4 + r;
        u16 hq = f2h(__expf(acc[mf][nf][r] - mx));   // <= 1, no overflow
        STb[(size_t)row * NN + col] = hq;
        s += h2f(hq);                                // Z from the quantized values pv will read
      }
    }
    s += __shfl_xor(s, 16);
    s += __shfl_xor(s, 32);
    if (lane < 16) {
      size_t idx = (size_t)chunk * MTOT + (size_t)bz * NN + col;
      Mpart[idx] = mx;
      Zpart[idx] = s;
    }
  }
}

// combine 16 chunk partials: M = max, Z = sum cfac*Zc; emit cfac16[chunk][i] = fp16(exp(Mc-M))
__global__ void mzreduce(const float* __restrict__ Mpart, const float* __restrict__ Zpart,
                         u16* __restrict__ cfac16, float* __restrict__ Zrow) {
  int i = blockIdx.x * 256 + threadIdx.x;   // 16384
  float M = Mpart[i];
#pragma unroll
  for (int c = 1; c < 16; ++c) M = fmaxf(M, Mpart[(size_t)c * MTOT + i]);
  float Z = 0.0f;
#pragma unroll
  for (int c = 0; c < 16; ++c) {
    u16 cq = f2h(__expf(Mpart[(size_t)c * MTOT + i] - M));
    cfac16[(size_t)c * MTOT + i] = cq;
    Z += h2f(cq) * Zpart[(size_t)c * MTOT + i];   // consistent with pv's fp16 cfac
  }
  Zrow[i] = Z;
}

// ---------------- fused PV GEMM: out[n][d] = sum_m (E'[n][m]*cfac[m]) * X3T'[d][m] + Xb[n][d]
// round-9 structure (single-buffer, 24KB LDS); staging is now 8 pk-muls, no exp.
__global__ __launch_bounds__(256)
void gemm_pv(const u16* __restrict__ ST, const u16* __restrict__ cfac16,
             const u16* __restrict__ X3T, const u16* __restrict__ Xb,
             float* __restrict__ out) {
  const int bz = blockIdx.z;
  const u16* Sb = ST + (size_t)bz * NN * NN;
  const u16* Bb = X3T + (size_t)bz * (size_t)ND * NN;
  const int row0 = blockIdx.x * 64;        // n tile (inside one 128-row chunk)
  const u16* Cb = cfac16 + (size_t)(blockIdx.x >> 1) * MTOT + (size_t)bz * NN;
  const int col0 = blockIdx.y * 128;       // d tile
  __shared__ __attribute__((aligned(16))) u16 As[64 * 64];
  __shared__ __attribute__((aligned(16))) u16 Bs[128 * 64];
  const int tid = threadIdx.x, lane = tid & 63, wave = tid >> 6;
  const int wr = (wave >> 1) * 32, wc = (wave & 1) * 64;
  const int lr = lane & 15, lk8 = (lane >> 4) * 8;
  const int arow = tid >> 3;               // 0..31
  const int akc  = (tid & 7) * 8;          // 0..56
  f32x4 acc[2][4] = {};
  for (int kt = 0; kt < NN; kt += 64) {
    // B (X3T rows d, k=m contiguous) async direct-to-LDS
#pragma unroll
    for (int i = 0; i < 4; ++i) {
      int e = i * 256 + tid;
      int r = e >> 3, kc = (e & 7) * 8;
      gld_lds16(Bb + (size_t)(col0 + r) * NN + kt + kc, Bs + e * 8);
    }
    // A = E' * cfac (packed fp16 mul, no exp)
    u32x4 s0 = *(const u32x4*)&Sb[(size_t)(row0 + arow) * NN + kt + akc];
    u32x4 s1 = *(const u32x4*)&Sb[(size_t)(row0 + arow + 32) * NN + kt + akc];
    u32x4 cv = *(const u32x4*)&Cb[kt + akc];
    f16x8 c8 = __builtin_bit_cast(f16x8, cv);
    f16x8 e0 = __builtin_bit_cast(f16x8, s0) * c8;
    f16x8 e1 = __builtin_bit_cast(f16x8, s1) * c8;
    *(u32x4*)&As[arow * 64 + akc] = __builtin_bit_cast(u32x4, e0);
    *(u32x4*)&As[(arow + 32) * 64 + akc] = __builtin_bit_cast(u32x4, e1);
    __syncthreads();
#pragma unroll
    for (int kk = 0; kk < 2; ++kk) {
      f16x8 af[2], bg[4];
      const int ko = kk * 32 + lk8;
#pragma unroll
      for (int m = 0; m < 2; ++m)
        af[m] = __builtin_bit_cast(f16x8, *(const u32x4*)&As[(wr + m * 16 + lr) * 64 + ko]);
#pragma unroll
      for (int n = 0; n < 4; ++n)
        bg[n] = __builtin_bit_cast(f16x8, *(const u32x4*)&Bs[(wc + n * 16 + lr) * 64 + ko]);
#pragma unroll
      for (int m = 0; m < 2; ++m)
#pragma unroll
        for (int n = 0; n < 4; ++n)
          acc[m][n] = __builtin_amdgcn_mfma_f32_16x16x32_f16(af[m], bg[n], acc[m][n], 0, 0, 0);
    }
    __syncthreads();
  }
  const int lq4 = (lane >> 4) * 4;
#pragma unroll
  for (int m = 0; m < 2; ++m) {
#pragma unroll
    for (int n = 0; n < 4; ++n) {
      const int col = col0 + wc + n * 16 + lr;
#pragma unroll
      for (int r = 0; r < 4; ++r) {
        const int row = row0 + wr + m * 16 + lq4 + r;
        float v = acc[m][n][r] + h2f(Xb[((size_t)bz * NN + row) * ND + col]);
        out[((size_t)bz * NN + row) * (size_t)ND + col] = v;
      }
    }
  }
}

// ---------------- BatchNorm stats / apply (Y in fp16) ----------------

__global__ void bn_stats(const u16* __restrict__ Yh, float* __restrict__ sums) {
  int t = threadIdx.x;                       // 0..191
  const ushort4* p = (const ushort4*)Yh + (size_t)blockIdx.x * 128 * 192 + t;
  float s0 = 0, s1 = 0, s2 = 0, s3 = 0, q0 = 0, q1 = 0, q2 = 0, q3 = 0;
  for (int r = 0; r < 128; ++r) {
    ushort4 v = p[(size_t)r * 192];
    float a = h2f(v.x), b = h2f(v.y), c = h2f(v.z), d = h2f(v.w);
    s0 += a; s1 += b; s2 += c; s3 += d;
    q0 += a * a; q1 += b * b; q2 += c * c; q3 += d * d;
  }
  int c = t * 4;
  atomicAdd(&sums[c + 0], s0); atomicAdd(&sums[c + 1], s1);
  atomicAdd(&sums[c + 2], s2); atomicAdd(&sums[c + 3], s3);
  atomicAdd(&sums[CCH + c + 0], q0); atomicAdd(&sums[CCH + c + 1], q1);
  atomicAdd(&sums[CCH + c + 2], q2); atomicAdd(&sums[CCH + c + 3], q3);
}

__global__ void bn_finalize(const float* __restrict__ sums,
                            const float* __restrict__ g1, const float* __restrict__ be1,
                            const float* __restrict__ g2, const float* __restrict__ be2,
                            const float* __restrict__ g3, const float* __restrict__ be3,
                            float* __restrict__ scale, float* __restrict__ shift) {
  int c = blockIdx.x * 256 + threadIdx.x;
  if (c >= CCH) return;
  const float inv = 1.0f / (float)MTOT;
  float mu  = sums[c] * inv;
  float var = sums[CCH + c] * inv - mu * mu;
  float g, be;
  if (c < 128)      { g = g1[c];       be = be1[c]; }
  else if (c < 256) { g = g2[c - 128]; be = be2[c - 128]; }
  else              { g = g3[c - 256]; be = be3[c - 256]; }
  float sc = rsqrtf(var + 1e-5f) * g;
  scale[c] = sc;
  shift[c] = be - mu * sc;
}

__global__ void bn_apply_route(const u16* __restrict__ Yh, const float* __restrict__ scale,
                               const float* __restrict__ shift, u16* __restrict__ X1b,
                               u16* __restrict__ X2b, u16* __restrict__ X3b) {
  size_t idx4 = (size_t)blockIdx.x * 256 + threadIdx.x;   // 16384*192 total
  int row = (int)(idx4 / 192);
  int c4  = (int)(idx4 % 192);
  int c   = c4 * 4;
  ushort4 y = ((const ushort4*)Yh)[idx4];
  float4 sc = ((const float4*)scale)[c4];
  float4 sh = ((const float4*)shift)[c4];
  ushort4 o;
  o.x = f2h(h2f(y.x) * sc.x + sh.x);
  o.y = f2h(h2f(y.y) * sc.y + sh.y);
  o.z = f2h(h2f(y.z) * sc.z + sh.z);
  o.w = f2h(h2f(y.w) * sc.w + sh.w);
  if (c < 128)      *(ushort4*)&X1b[(size_t)row * 128 + c] = o;
  else if (c < 256) *(ushort4*)&X2b[(size_t)row * 128 + (c - 128)] = o;
  else              *(ushort4*)&X3b[(size_t)row * 512 + (c - 256)] = o;
}

// ---------------- X3 transpose with 1/Z fold ----------------

__global__ void transpose_scale(const u16* __restrict__ in, const float* __restrict__ Zrow,
                                u16* __restrict__ out, int R, int C) {
  // per-batch [R][C] -> [C][R], scaling row m by 1/Zrow[bz*R+m]
  __shared__ u16 tile[64][66];
  int bz = blockIdx.z;
  const u16* ib = in + (size_t)bz * R * C;
  u16* ob = out + (size_t)bz * R * C;
  int r0 = blockIdx.x * 64, c0 = blockIdx.y * 64;
  int t = threadIdx.x, tr = t >> 4, tc4 = (t & 15) * 4;
#pragma unroll
  for (int i = 0; i < 4; ++i) {
    int rl = i * 16 + tr;
    float iz = 1.0f / Zrow[(size_t)bz * R + r0 + rl];
    ushort4 v = *(const ushort4*)&ib[(size_t)(r0 + rl) * C + c0 + tc4];
    tile[tc4 + 0][rl] = f2h(h2f(v.x) * iz);
    tile[tc4 + 1][rl] = f2h(h2f(v.y) * iz);
    tile[tc4 + 2][rl] = f2h(h2f(v.z) * iz);
    tile[tc4 + 3][rl] = f2h(h2f(v.w) * iz);
  }
  __syncthreads();
#pragma unroll
  for (int i = 0; i < 4; ++i) {
    int cl = i * 16 + tr;
    ushort4 o;
    o.x = tile[cl][tc4 + 0]; o.y = tile[cl][tc4 + 1];
    o.z = tile[cl][tc4 + 2]; o.w = tile[cl][tc4 + 3];
    *(ushort4*)&ob[(size_t)(c0 + cl) * R + r0 + tc4] = o;
  }
}

// ---------------- launch ----------------

extern "C" void kernel_launch(void* const* d_in, const int* in_sizes, int n_in,
                              void* d_out, int out_size, void* d_ws, size_t ws_size,
                              hipStream_t stream) {
  const float* X   = (const float*)d_in[0];
  const float* W1  = (const float*)d_in[1];
  const float* b1  = (const float*)d_in[2];
  const float* g1  = (const float*)d_in[3];
  const float* be1 = (const float*)d_in[4];
  const float* W2  = (const float*)d_in[5];
  const float* b2  = (const float*)d_in[6];
  const float* g2  = (const float*)d_in[7];
  const float* be2 = (const float*)d_in[8];
  const float* W3  = (const float*)d_in[9];
  const float* b3  = (const float*)d_in[10];
  const float* g3  = (const float*)d_in[11];
  const float* be3 = (const float*)d_in[12];
  float* out = (float*)d_out;

  char* ws = (char*)d_ws;
  // small region
  float* sums  = (float*)ws;                 // 1536
  float* scale = sums + 1536;                // 768
  float* shift = scale + 768;                // 768
  float* bcat  = shift + 768;                // 768
  float* Zrow  = bcat + 768;                 // 16384
  float* Mpart = Zrow + 16384;               // 16*16384
  float* Zpart = Mpart + 16 * 16384;         // 16*16384
  u16*   cfac16 = (u16*)(Zpart + 16 * 16384);  // 16*16384 u16 = 512KB
  size_t off = (size_t)(1536 + 768 + 768 + 768 + 16384 + 32 * 16384) * 4
             + (size_t)16 * 16384 * 2;
  off = (off + 255) & ~(size_t)255;
  // persistent fp16 region
  u16* X1b = (u16*)(ws + off); off += (size_t)MTOT * 128 * 2;
  u16* X2b = (u16*)(ws + off); off += (size_t)MTOT * 128 * 2;
  u16* X3b = (u16*)(ws + off); off += (size_t)MTOT * 512 * 2;
  u16* X3T = (u16*)(ws + off); off += (size_t)MTOT * 512 * 2;
  u16* Xb  = (u16*)(ws + off); off += (size_t)MTOT * 512 * 2;
  // union region: {Wcat, Yh} (dead before ST is written) overlaid with fp16 ST (holds E')
  char* uni = ws + off;
  u16* Wcat = (u16*)uni;                               // 768 KB
  u16* Yh   = (u16*)(uni + 768 * 512 * 2);             // 24 MB fp16
  u16* ST   = (u16*)uni;                               // 64 MB fp16 (E' values)
  size_t total = off + (size_t)NB * NN * NN * 2;
  if (ws_size < total) return;  // workspace too small: fail visibly

  hipMemsetAsync(sums, 0, 1536 * sizeof(float), stream);

  cvt_f32_f16<<<8192, 256, 0, stream>>>(X, Xb, (size_t)MTOT * 512 / 4);
  assemble_w<<<384, 256, 0, stream>>>(W1, W2, W3, b1, b2, b3, Wcat, bcat);

  // proj GEMM: Yh[16384][768] = fp16(leaky(Xb @ Wcat^T + bcat))
  gemm_bt<EPI_BIAS_LEAKY, 128, 128, true><<<dim3(128, 6, 1), 256, 0, stream>>>(
      Xb, Wcat, Yh, CCH, 512, 0, 0, 0, bcat);

  bn_stats<<<128, 192, 0, stream>>>(Yh, sums);
  bn_finalize<<<3, 256, 0, stream>>>(sums, g1, be1, g2, be2, g3, be3, scale, shift);
  bn_apply_route<<<12288, 256, 0, stream>>>(Yh, scale, shift, X1b, X2b, X3b);

  // E'[b][n][m] = fp16(exp(X1.X2 - M_chunk)) one-shot + chunk col-max/Z partials
  gemm_s<<<dim3(8, 8, 8), 512, 0, stream>>>(X1b, X2b, ST, Mpart, Zpart);
  mzreduce<<<64, 256, 0, stream>>>(Mpart, Zpart, cfac16, Zrow);

  // X3T[d][m] = fp16(X3[m][d] / Z[m])
  transpose_scale<<<dim3(32, 8, 8), 256, 0, stream>>>(X3b, Zrow, X3T, 2048, 512);

  // out[b][n][d] = sum_m E'[n][m]*cfac[m] * X3T[d][m] + Xb[n][d]
  gemm_pv<<<dim3(32, 4, 8), 256, 0, stream>>>(ST, cfac16, X3T, Xb, out);
}